// Round 1
// baseline (895.900 us; speedup 1.0000x reference)
//
#include <hip/hip_runtime.h>

#define BQ   2
#define QQ   65536
#define HID  256
#define ENC  64
#define NPIX 4096          // 64*64
#define NROW (BQ*QQ*4)     // 524288
#define KCONV 576          // ENC*9

using bf16x8 = __bf16 __attribute__((ext_vector_type(8)));
using f32x4  = float  __attribute__((ext_vector_type(4)));

__device__ __forceinline__ unsigned short f2bf(float f){
  unsigned u = __float_as_uint(f);
  u = (u + 0x7fffu + ((u >> 16) & 1u)) >> 16;
  return (unsigned short)u;
}

// byte offset of bf16 element (row,col) in a [128][256] bf16 LDS tile,
// XOR-swizzled at 16B granularity to avoid stride-512B bank conflicts (G4).
__device__ __forceinline__ int xaddr(int row, int col){
  return row*512 + ((((col >> 3) ^ (row & 7)) << 4) | ((col & 7) << 1));
}

// ---------------- prep: weight conversion + BN sum zeroing ----------------
__global__ void prep_kernel(const float* coef_w, const float* freq_w,
                            const float* w0, const float* w1,
                            const float* w2, const float* w3,
                            const float* wo,
                            unsigned short* Wcat, unsigned short* Wmlp,
                            unsigned short* wo_pad, float* bnsums){
  int idx = blockIdx.x*256 + threadIdx.x;
  if (idx < 8) bnsums[idx] = 0.f;
  if (idx < 512*KCONV){
    int n = idx / KCONV, k = idx % KCONV;
    const float* src = (n < 256) ? coef_w : freq_w;
    Wcat[idx] = f2bf(src[(n & 255)*KCONV + k]);
    return;
  }
  int i2 = idx - 512*KCONV;
  if (i2 < 4*65536){
    const float* wl = (i2 < 65536) ? w0 : (i2 < 131072) ? w1
                     : (i2 < 196608) ? w2 : w3;
    Wmlp[i2] = f2bf(wl[i2 & 65535]);
    return;
  }
  int i3 = i2 - 4*65536;
  if (i3 < 16*256){
    int c = i3 >> 8, k = i3 & 255;
    wo_pad[i3] = (c < 3) ? f2bf(wo[c*256 + k]) : (unsigned short)0;
  }
}

// ---------------- enc conv: (B,3,64,64) -> feat (B,64,64,64) f32 ----------
__global__ void enc_conv_kernel(const float* inp, const float* enc_w,
                                const float* enc_b, float* feat){
  __shared__ float wl[ENC*27];
  __shared__ float bl[ENC];
  int t = threadIdx.x;
  for (int i = t; i < ENC*27; i += 256) wl[i] = enc_w[i];
  if (t < ENC) bl[t] = enc_b[t];
  __syncthreads();
  int p  = blockIdx.x*256 + t;      // 0..8191
  int b  = p >> 12, yx = p & 4095;
  int y  = yx >> 6, x = yx & 63;
  float v[27];
  #pragma unroll
  for (int c = 0; c < 3; c++)
    #pragma unroll
    for (int dy = 0; dy < 3; dy++)
      #pragma unroll
      for (int dx = 0; dx < 3; dx++){
        int yy = y + dy - 1, xx = x + dx - 1;
        v[c*9 + dy*3 + dx] = (yy >= 0 && yy < 64 && xx >= 0 && xx < 64)
                             ? inp[(b*3 + c)*NPIX + yy*64 + xx] : 0.f;
      }
  for (int o = 0; o < ENC; o++){
    float acc = bl[o];
    #pragma unroll
    for (int k = 0; k < 27; k++) acc += wl[o*27 + k] * v[k];
    feat[(b*ENC + o)*NPIX + yx] = acc;
  }
}

// ---------------- im2col: feat -> P bf16 [8192][576] ----------------------
__global__ void im2col_kernel(const float* feat, unsigned short* P){
  int idx = blockIdx.x*256 + threadIdx.x;
  int pix = idx / KCONV, k = idx % KCONV;
  int b = pix >> 12, yx = pix & 4095;
  int y = yx >> 6, x = yx & 63;
  int cin = k / 9, j = k % 9;
  int yy = y + j/3 - 1, xx = x + (j%3) - 1;
  float v = (yy >= 0 && yy < 64 && xx >= 0 && xx < 64)
            ? feat[(b*ENC + cin)*NPIX + yy*64 + xx] : 0.f;
  P[idx] = f2bf(v);
}

// ---------------- conv GEMM: coef/freq, pixel-major f32 out ---------------
__global__ __launch_bounds__(256)
void conv_gemm_kernel(const unsigned short* P, const unsigned short* Wcat,
                      const float* coef_b, const float* freq_b,
                      float* coefT, float* freqT){
  int wave = threadIdx.x >> 6, lane = threadIdx.x & 63;
  int tile = blockIdx.x*4 + wave;           // 0..16383
  int mt = tile >> 5, nt = tile & 31;
  int l16 = lane & 15, g = lane >> 4;
  int arow = mt*16 + l16;
  int ncol = nt*16 + l16;
  const unsigned short* Ap = P    + arow*KCONV + g*8;
  const unsigned short* Bp = Wcat + ncol*KCONV + g*8;
  f32x4 acc = {0.f, 0.f, 0.f, 0.f};
  #pragma unroll
  for (int kk = 0; kk < 18; kk++){
    bf16x8 a   = *(const bf16x8*)(Ap + kk*32);
    bf16x8 bfr = *(const bf16x8*)(Bp + kk*32);
    acc = __builtin_amdgcn_mfma_f32_16x16x32_bf16(a, bfr, acc, 0, 0, 0);
  }
  float bias = (ncol < 256) ? coef_b[ncol] : freq_b[ncol - 256];
  #pragma unroll
  for (int r = 0; r < 4; r++){
    int row = mt*16 + g*4 + r;               // pixel index
    float vv = acc[r] + bias;
    if (ncol < 256) coefT[row*256 + ncol]        = vv;
    else            freqT[row*256 + (ncol-256)]  = vv;
  }
}

// ---------------- fused gather/fourier + 4-layer MLP + out layer ----------
__global__ __launch_bounds__(512, 4)
void mlp_kernel(const float* coefT, const float* freqT,
                const float* coord, const float* cell, const float* phase_w,
                const unsigned short* Wmlp,
                const float* b0, const float* b1, const float* b2, const float* b3,
                const unsigned short* wo_pad, const float* bo,
                float* areas, float* pred){
  __shared__ __align__(16) char Xs[128*256*2];   // 64 KiB, swizzled bf16 [128][256]
  int t = threadIdx.x;
  int r0 = blockIdx.x*128;
  int wave = t >> 6, lane = t & 63;
  int l16 = lane & 15, g = lane >> 4;

  // ---- build X (gather + fourier), one wave per row, coalesced ----
  for (int rr = 0; rr < 16; rr++){
    int lr = wave*16 + rr;
    int gr = r0 + lr;
    int s  = gr & 3, bq = gr >> 2;
    float c0 = coord[bq*2], c1 = coord[bq*2+1];
    float ce0 = cell[bq*2]*64.f, ce1 = cell[bq*2+1]*64.f;
    float vx = (s & 2) ? 1.f : -1.f;
    float vy = (s & 1) ? 1.f : -1.f;
    const float RX = 1.f/64.f;
    float cy = fminf(fmaxf(c0 + vx*RX + 1e-6f, -1.f + 1e-6f), 1.f - 1e-6f);
    float cx = fminf(fmaxf(c1 + vy*RX + 1e-6f, -1.f + 1e-6f), 1.f - 1e-6f);
    int iy = min(max((int)rintf((cy + 1.f)*32.f - 0.5f), 0), 63);
    int ix = min(max((int)rintf((cx + 1.f)*32.f - 0.5f), 0), 63);
    float qy = -1.f + (2*iy + 1)*(1.f/64.f);
    float qx = -1.f + (2*ix + 1)*(1.f/64.f);
    float rel0 = (c0 - qy)*64.f, rel1 = (c1 - qx)*64.f;
    if (lane == 0) areas[gr] = fabsf(rel0*rel1) + 1e-9f;
    int b = bq >> 16;
    int pix = b*NPIX + iy*64 + ix;
    const float* cR = coefT + pix*256;
    const float* fR = freqT + pix*256;
    #pragma unroll
    for (int hh = 0; hh < 2; hh++){
      int p = hh*64 + lane;                       // pair index 0..127
      float2 fv = *(const float2*)(fR + 2*p);
      float2 pw = *(const float2*)(phase_w + 2*p);
      float qf = fv.x*rel0 + fv.y*rel1 + ce0*pw.x + ce1*pw.y;
      float cv = cospif(qf), sv = sinpif(qf);
      float xlo = cR[p]       * cv;
      float xhi = cR[128 + p] * sv;
      *(unsigned short*)(Xs + xaddr(lr, p))       = f2bf(xlo);
      *(unsigned short*)(Xs + xaddr(lr, 128 + p)) = f2bf(xhi);
    }
  }
  __syncthreads();

  const float* bls[4] = {b0, b1, b2, b3};
  int n0 = wave*32;      // this wave owns output cols n0..n0+31 each layer

  #pragma unroll
  for (int l = 0; l < 4; l++){
    const unsigned short* Wl = Wmlp + l*65536;
    float bias0 = bls[l][n0 + l16];
    float bias1 = bls[l][n0 + 16 + l16];
    f32x4 acc[8][2];
    #pragma unroll
    for (int m = 0; m < 8; m++){
      acc[m][0] = {bias0, bias0, bias0, bias0};
      acc[m][1] = {bias1, bias1, bias1, bias1};
    }
    #pragma unroll
    for (int kk = 0; kk < 8; kk++){
      bf16x8 bf0 = *(const bf16x8*)(Wl + (n0 + l16)*256      + kk*32 + g*8);
      bf16x8 bf1 = *(const bf16x8*)(Wl + (n0 + 16 + l16)*256 + kk*32 + g*8);
      #pragma unroll
      for (int m = 0; m < 8; m++){
        bf16x8 a = *(const bf16x8*)(Xs + xaddr(m*16 + l16, kk*32 + g*8));
        acc[m][0] = __builtin_amdgcn_mfma_f32_16x16x32_bf16(a, bf0, acc[m][0], 0,0,0);
        acc[m][1] = __builtin_amdgcn_mfma_f32_16x16x32_bf16(a, bf1, acc[m][1], 0,0,0);
      }
    }
    __syncthreads();            // all reads of Xs done -> safe to overwrite
    #pragma unroll
    for (int m = 0; m < 8; m++)
      #pragma unroll
      for (int j = 0; j < 2; j++){
        int col = n0 + j*16 + l16;
        #pragma unroll
        for (int r = 0; r < 4; r++){
          int row = m*16 + g*4 + r;
          *(unsigned short*)(Xs + xaddr(row, col)) =
              f2bf(fmaxf(acc[m][j][r], 0.f));
        }
      }
    __syncthreads();
  }

  // ---- output layer (wo padded to 16 rows), wave w -> M-tile w ----
  {
    float bias = (l16 < 3) ? bo[l16] : 0.f;
    f32x4 acc = {bias, bias, bias, bias};
    #pragma unroll
    for (int kk = 0; kk < 8; kk++){
      bf16x8 bfr = *(const bf16x8*)(wo_pad + l16*256 + kk*32 + g*8);
      bf16x8 a   = *(const bf16x8*)(Xs + xaddr(wave*16 + l16, kk*32 + g*8));
      acc = __builtin_amdgcn_mfma_f32_16x16x32_bf16(a, bfr, acc, 0, 0, 0);
    }
    if (l16 < 3){
      #pragma unroll
      for (int r = 0; r < 4; r++){
        int row = wave*16 + g*4 + r;
        pred[(r0 + row)*3 + l16] = acc[r];
      }
    }
  }
}

// ---------------- combine: area blend + bilinear residual + BN sums -------
__global__ void combine_kernel(const float* pred, const float* areas,
                               const float* coord, const float* inp,
                               float* retbuf, float* bnsums){
  int bq = blockIdx.x*256 + threadIdx.x;   // 0..131071
  int b  = bq >> 16;
  float4 ar = *(const float4*)(areas + bq*4);
  float tot = ar.x + ar.y + ar.z + ar.w;
  float w0_ = ar.w/tot, w1_ = ar.z/tot, w2_ = ar.y/tot, w3_ = ar.x/tot;
  const float* pp = pred + bq*12;
  float r_[3];
  #pragma unroll
  for (int c = 0; c < 3; c++)
    r_[c] = pp[c]*w0_ + pp[3+c]*w1_ + pp[6+c]*w2_ + pp[9+c]*w3_;

  float c0 = coord[bq*2], c1 = coord[bq*2+1];
  float fy = (c0 + 1.f)*32.f - 0.5f, fx = (c1 + 1.f)*32.f - 0.5f;
  float y0f = floorf(fy), x0f = floorf(fx);
  float wy = fy - y0f, wx = fx - x0f;
  int y0 = min(max((int)y0f, 0), 63), y1 = min(max((int)y0f + 1, 0), 63);
  int x0 = min(max((int)x0f, 0), 63), x1 = min(max((int)x0f + 1, 0), 63);
  const float* ib = inp + b*3*NPIX;
  #pragma unroll
  for (int c = 0; c < 3; c++){
    const float* pl = ib + c*NPIX;
    float v00 = pl[y0*64 + x0], v01 = pl[y0*64 + x1];
    float v10 = pl[y1*64 + x0], v11 = pl[y1*64 + x1];
    r_[c] += v00*(1.f-wy)*(1.f-wx) + v01*(1.f-wy)*wx
           + v10*wy*(1.f-wx)       + v11*wy*wx;
    retbuf[bq*3 + c] = r_[c];
  }
  #pragma unroll
  for (int c = 0; c < 3; c++){
    float s = r_[c], ss = r_[c]*r_[c];
    #pragma unroll
    for (int off = 32; off; off >>= 1){
      s  += __shfl_down(s,  off);
      ss += __shfl_down(ss, off);
    }
    if ((threadIdx.x & 63) == 0){
      atomicAdd(&bnsums[c],     s);
      atomicAdd(&bnsums[4 + c], ss);
    }
  }
}

// ---------------- batchnorm normalize -------------------------------------
__global__ void normalize_kernel(const float* retbuf, const float* bnsums,
                                 const float* gamma, const float* beta,
                                 float* out){
  int idx = blockIdx.x*256 + threadIdx.x;
  if (idx >= BQ*QQ*3) return;
  int c = idx % 3;
  const float n = (float)(BQ*QQ);
  float mean = bnsums[c] / n;
  float var  = bnsums[4 + c] / n - mean*mean;
  out[idx] = (retbuf[idx] - mean) * rsqrtf(var + 1e-5f) * gamma[c] + beta[c];
}

extern "C" void kernel_launch(void* const* d_in, const int* in_sizes, int n_in,
                              void* d_out, int out_size, void* d_ws, size_t ws_size,
                              hipStream_t stream){
  const float* inp    = (const float*)d_in[0];
  const float* coord  = (const float*)d_in[1];
  const float* cell   = (const float*)d_in[2];
  const float* enc_w  = (const float*)d_in[3];
  const float* enc_b  = (const float*)d_in[4];
  const float* coef_w = (const float*)d_in[5];
  const float* coef_b = (const float*)d_in[6];
  const float* freq_w = (const float*)d_in[7];
  const float* freq_b = (const float*)d_in[8];
  const float* phase_w= (const float*)d_in[9];
  const float* w0 = (const float*)d_in[10]; const float* b0 = (const float*)d_in[11];
  const float* w1 = (const float*)d_in[12]; const float* b1 = (const float*)d_in[13];
  const float* w2 = (const float*)d_in[14]; const float* b2 = (const float*)d_in[15];
  const float* w3 = (const float*)d_in[16]; const float* b3 = (const float*)d_in[17];
  const float* wo = (const float*)d_in[18]; const float* bo = (const float*)d_in[19];
  const float* gamma = (const float*)d_in[20]; const float* beta = (const float*)d_in[21];

  char* ws = (char*)d_ws;
  float*          feat   = (float*)(ws + 0);              // 2 MB
  unsigned short* P      = (unsigned short*)(ws + 2097152);   // 9.44 MB
  unsigned short* Wcat   = (unsigned short*)(ws + 11534336);  // 576 KB
  float*          coefT  = (float*)(ws + 12124160);       // 8 MB
  float*          freqT  = (float*)(ws + 20512768);       // 8 MB
  unsigned short* Wmlp   = (unsigned short*)(ws + 28901376);  // 512 KB
  unsigned short* wo_pad = (unsigned short*)(ws + 29425664);  // 8 KB
  float*          areas  = (float*)(ws + 29433856);       // 2 MB
  float*          pred   = (float*)(ws + 31531008);       // 6 MB
  float*          retbuf = (float*)(ws + 37822464);       // 1.5 MB
  float*          bnsums = (float*)(ws + 39395328);       // 32 B
  if (ws_size < 39395360) return;

  prep_kernel<<<2192, 256, 0, stream>>>(coef_w, freq_w, w0, w1, w2, w3, wo,
                                        Wcat, Wmlp, wo_pad, bnsums);
  enc_conv_kernel<<<32, 256, 0, stream>>>(inp, enc_w, enc_b, feat);
  im2col_kernel<<<18432, 256, 0, stream>>>(feat, P);
  conv_gemm_kernel<<<4096, 256, 0, stream>>>(P, Wcat, coef_b, freq_b, coefT, freqT);
  mlp_kernel<<<4096, 512, 0, stream>>>(coefT, freqT, coord, cell, phase_w, Wmlp,
                                       b0, b1, b2, b3, wo_pad, bo, areas, pred);
  combine_kernel<<<512, 256, 0, stream>>>(pred, areas, coord, inp, retbuf, bnsums);
  normalize_kernel<<<1536, 256, 0, stream>>>(retbuf, bnsums, gamma, beta,
                                             (float*)d_out);
}